// Round 3
// baseline (2103.758 us; speedup 1.0000x reference)
//
#include <hip/hip_runtime.h>
#include <math.h>

// ---------------------------------------------------------------------------
// RecurrentNatureCNN: conv1(8x8,s4) -> conv2(4x4,s2) -> conv3(3x3,s1) -> FC
//                     -> LSTM(T=64,B=32,H=256)
// fp32. N = T*B = 2048 images.
// R2: LSTM -> 256 blocks (1 unit each, weights LDS-resident), flag-based
//     cross-block pipeline (device-scope atomics), h broadcast via L3.
//     Kills the 2 GB/launch weight re-read that made R1's LSTM L1-bound.
// ---------------------------------------------------------------------------

#define NIMG 2048

// ---- generic small transpose: in (R,C) -> out (C,R) -----------------------
__global__ void transpose_kernel(const float* __restrict__ in, float* __restrict__ out,
                                 int R, int C) {
    int idx = blockIdx.x * 256 + threadIdx.x;
    if (idx < R * C) {
        int r = idx / C, c = idx - r * C;
        out[c * R + r] = in[idx];
    }
}

// ---- conv1: x (n,4,64,64)/255 -> relu -> (n,32,15,15) ----------------------
// block = 1 image, 1024 threads (16 waves). wave w: oc-group g=w&3 (8 oc),
// position segment (w>>2)*64+lane. Image staged in LDS (64 KB -> 2 blocks/CU
// = 32 waves/CU).
__global__ __launch_bounds__(1024) void conv1_kernel(const float* __restrict__ x,
                                                     const float* __restrict__ w,
                                                     const float* __restrict__ b,
                                                     float* __restrict__ out) {
    __shared__ float xs[4 * 64 * 64];  // 65536 B
    int n = blockIdx.x;
    int tid = threadIdx.x;
    const float* xp = x + (size_t)n * 16384;
    const float inv = 1.0f / 255.0f;
    for (int i = tid * 4; i < 16384; i += 4096) {
        float4 v = *(const float4*)(xp + i);
        xs[i + 0] = v.x * inv;
        xs[i + 1] = v.y * inv;
        xs[i + 2] = v.z * inv;
        xs[i + 3] = v.w * inv;
    }
    __syncthreads();
    int lane = tid & 63, wave = tid >> 6;
    int gg = __builtin_amdgcn_readfirstlane(wave & 3);  // oc group, wave-uniform
    int pos = (wave >> 2) * 64 + lane;                  // 0..255
    if (pos < 225) {
        int oy = pos / 15, ox = pos - oy * 15;
        float acc[8];
        const float* bp = b + gg * 8;
#pragma unroll
        for (int u = 0; u < 8; ++u) acc[u] = bp[u];
        for (int ic = 0; ic < 4; ++ic) {
#pragma unroll
            for (int ky = 0; ky < 8; ++ky) {
                const float* xrow = &xs[(ic * 64 + oy * 4 + ky) * 64 + ox * 4];
                float xr[8];
                *(float4*)&xr[0] = *(const float4*)&xrow[0];
                *(float4*)&xr[4] = *(const float4*)&xrow[4];
                const float* wrow = w + (gg * 8) * 256 + ic * 64 + ky * 8;
#pragma unroll
                for (int u = 0; u < 8; ++u) {
                    const float* wr = wrow + u * 256;
#pragma unroll
                    for (int kx = 0; kx < 8; ++kx) acc[u] += xr[kx] * wr[kx];
                }
            }
        }
        float* op = out + (size_t)n * 7200 + (gg * 8) * 225 + pos;
#pragma unroll
        for (int u = 0; u < 8; ++u) op[u * 225] = fmaxf(acc[u], 0.0f);
    }
}

// ---- conv2: z1 (n,32,15,15) -> relu -> (n,64,6,6) --------------------------
__global__ __launch_bounds__(256) void conv2_kernel(const float* __restrict__ x,
                                                    const float* __restrict__ wt,
                                                    const float* __restrict__ bias,
                                                    float* __restrict__ out) {
    __shared__ float xs[2][32 * 15 * 16];  // 61440 B
    int tid = threadIdx.x;
    int n0 = blockIdx.x * 2;
    for (int img = 0; img < 2; ++img) {
        const float* src = x + (size_t)(n0 + img) * 7200;
        for (int s = tid; s < 7200; s += 256) {
            int ic = s / 225;
            int rem = s - ic * 225;
            int r = rem / 15;
            int c = rem - r * 15;
            xs[img][(ic * 15 + r) * 16 + c] = src[s];
        }
    }
    __syncthreads();
    int lane = tid & 63, wave = tid >> 6;
    int img = wave >> 1;
    int rowHalf = wave & 1;
    int n = n0 + img;
    float bv = bias[lane];
    float* op = out + (size_t)n * 2304 + lane * 36;
    for (int q = 0; q < 3; ++q) {
        int oy = rowHalf * 3 + q;
        float acc[6];
#pragma unroll
        for (int u = 0; u < 6; ++u) acc[u] = bv;
        for (int ic = 0; ic < 32; ++ic) {
#pragma unroll
            for (int ky = 0; ky < 4; ++ky) {
                const float* xrow = &xs[img][(ic * 15 + oy * 2 + ky) * 16];
                float xr[16];
                *(float4*)&xr[0]  = *(const float4*)&xrow[0];
                *(float4*)&xr[4]  = *(const float4*)&xrow[4];
                *(float4*)&xr[8]  = *(const float4*)&xrow[8];
                *(float4*)&xr[12] = *(const float4*)&xrow[12];
                const float* wp = wt + ((ic * 4 + ky) * 4) * 64 + lane;
#pragma unroll
                for (int kx = 0; kx < 4; ++kx) {
                    float wv = wp[kx * 64];
#pragma unroll
                    for (int u = 0; u < 6; ++u) acc[u] += xr[u * 2 + kx] * wv;
                }
            }
        }
#pragma unroll
        for (int u = 0; u < 6; ++u) op[oy * 6 + u] = fmaxf(acc[u], 0.0f);
    }
}

// ---- conv3: z2 (n,64,6,6) -> relu -> (n,64,4,4) ----------------------------
__global__ __launch_bounds__(256) void conv3_kernel(const float* __restrict__ x,
                                                    const float* __restrict__ wt,
                                                    const float* __restrict__ bias,
                                                    float* __restrict__ out) {
    __shared__ float xs[4][64 * 6 * 8];  // 49152 B
    int tid = threadIdx.x;
    int n0 = blockIdx.x * 4;
    for (int img = 0; img < 4; ++img) {
        const float* src = x + (size_t)(n0 + img) * 2304;
        for (int s = tid; s < 2304; s += 256) {
            int ic = s / 36;
            int rem = s - ic * 36;
            int r = rem / 6;
            int c = rem - r * 6;
            xs[img][(ic * 6 + r) * 8 + c] = src[s];
        }
    }
    __syncthreads();
    int lane = tid & 63, wave = tid >> 6;
    int n = n0 + wave;
    float bv = bias[lane];
    float* op = out + (size_t)n * 1024 + lane * 16;
    for (int oy = 0; oy < 4; ++oy) {
        float acc[4];
#pragma unroll
        for (int u = 0; u < 4; ++u) acc[u] = bv;
        for (int ic = 0; ic < 64; ++ic) {
#pragma unroll
            for (int ky = 0; ky < 3; ++ky) {
                const float* xrow = &xs[wave][(ic * 6 + oy + ky) * 8];
                float xr[8];
                *(float4*)&xr[0] = *(const float4*)&xrow[0];
                *(float4*)&xr[4] = *(const float4*)&xrow[4];
                const float* wp = wt + ((ic * 3 + ky) * 3) * 64 + lane;
#pragma unroll
                for (int kx = 0; kx < 3; ++kx) {
                    float wv = wp[kx * 64];
#pragma unroll
                    for (int u = 0; u < 4; ++u) acc[u] += xr[u + kx] * wv;
                }
            }
        }
#pragma unroll
        for (int u = 0; u < 4; ++u) op[oy * 4 + u] = fmaxf(acc[u], 0.0f);
    }
}

// ---- GEMM: C(M,N) = [relu]( A(M,K) @ B(N,K)^T + bias [+ bias2] ) -----------
__global__ __launch_bounds__(256) void gemm_bt(const float* __restrict__ A,
                                               const float* __restrict__ B,
                                               const float* __restrict__ bias,
                                               const float* __restrict__ bias2,
                                               float* __restrict__ C,
                                               int M, int N, int K, int relu) {
    __shared__ float As[16][68];
    __shared__ float Bs[16][68];
    int tid = threadIdx.x;
    int m0 = blockIdx.y * 64, n0 = blockIdx.x * 64;
    int tx = tid & 15, ty = tid >> 4;
    int lr = tid >> 2;
    int lk = (tid & 3) * 4;
    const float* Ap = A + (size_t)(m0 + lr) * K + lk;
    const float* Bp = B + (size_t)(n0 + lr) * K + lk;
    float acc[4][4];
#pragma unroll
    for (int i = 0; i < 4; ++i)
#pragma unroll
        for (int j = 0; j < 4; ++j) acc[i][j] = 0.0f;

    for (int k0 = 0; k0 < K; k0 += 16) {
        float4 av = *(const float4*)(Ap + k0);
        float4 bv = *(const float4*)(Bp + k0);
        __syncthreads();
        As[lk + 0][lr] = av.x;
        As[lk + 1][lr] = av.y;
        As[lk + 2][lr] = av.z;
        As[lk + 3][lr] = av.w;
        Bs[lk + 0][lr] = bv.x;
        Bs[lk + 1][lr] = bv.y;
        Bs[lk + 2][lr] = bv.z;
        Bs[lk + 3][lr] = bv.w;
        __syncthreads();
#pragma unroll
        for (int kk = 0; kk < 16; ++kk) {
            float a[4], b[4];
            *(float4*)a = *(const float4*)&As[kk][ty * 4];
            *(float4*)b = *(const float4*)&Bs[kk][tx * 4];
#pragma unroll
            for (int i = 0; i < 4; ++i)
#pragma unroll
                for (int j = 0; j < 4; ++j) acc[i][j] += a[i] * b[j];
        }
    }
    float bb[4];
#pragma unroll
    for (int j = 0; j < 4; ++j) {
        float v = bias[n0 + tx * 4 + j];
        if (bias2) v += bias2[n0 + tx * 4 + j];
        bb[j] = v;
    }
#pragma unroll
    for (int i = 0; i < 4; ++i) {
        float4 o;
        o.x = acc[i][0] + bb[0];
        o.y = acc[i][1] + bb[1];
        o.z = acc[i][2] + bb[2];
        o.w = acc[i][3] + bb[3];
        if (relu) {
            o.x = fmaxf(o.x, 0.0f);
            o.y = fmaxf(o.y, 0.0f);
            o.z = fmaxf(o.z, 0.0f);
            o.w = fmaxf(o.w, 0.0f);
        }
        *(float4*)&C[(size_t)(m0 + ty * 4 + i) * N + n0 + tx * 4] = o;
    }
}

// ---- LSTM: 256 blocks x 1 wave; block u owns hidden unit u for all envs ----
// Weights: 4 rows of whh (gate g row g*256+u, contiguous 256 floats) -> LDS,
// loaded ONCE (no per-step weight traffic). Per step: stage h(t-1) (32 KB)
// from global into LDS; lane l: e = l&31, half = l>>5; half 0 computes gates
// i(0),g(2), half 1 computes f(1),o(3); 512 FMA/lane from LDS; one __shfl
// exchange; lower half updates (c,h) for (u,e) and scatters h/out.
// Cross-block sync: per-(step,unit) flags, release store + relaxed poll +
// __threadfence (agent scope handles cross-XCD L2 non-coherence).
__global__ __launch_bounds__(64) void lstm_kernel(const float* __restrict__ gi,
                                                  const float* __restrict__ whh,
                                                  const int* __restrict__ done,
                                                  const float* __restrict__ h0,
                                                  const float* __restrict__ c0,
                                                  float* h_buf,   // (64,32,256)
                                                  int* flags,     // (64,256)
                                                  float* __restrict__ out) {
    __shared__ float wlds[4][256];
    __shared__ float hlds[32 * 260];  // pad 260: 4-way max conflict on b128
    const int u = blockIdx.x;   // hidden unit 0..255
    const int l = threadIdx.x;  // 0..63
    const int e = l & 31;
    const int half = l >> 5;
    const int g0 = half, g1 = half + 2;

    // weight rows -> LDS (coalesced b128, once)
#pragma unroll
    for (int g = 0; g < 4; ++g) {
        float4 v = *(const float4*)(whh + (size_t)(g * 256 + u) * 256 + l * 4);
        *(float4*)&wlds[g][l * 4] = v;
    }
    float c = (half == 0) ? c0[e * 256 + u] : 0.0f;

    for (int t = 0; t < 64; ++t) {
        const float* hsrc;
        if (t == 0) {
            hsrc = h0;
        } else {
            const int* fl = flags + (t - 1) * 256 + l * 4;
            for (;;) {
                int f0 = __hip_atomic_load(fl + 0, __ATOMIC_RELAXED, __HIP_MEMORY_SCOPE_AGENT);
                int f1 = __hip_atomic_load(fl + 1, __ATOMIC_RELAXED, __HIP_MEMORY_SCOPE_AGENT);
                int f2 = __hip_atomic_load(fl + 2, __ATOMIC_RELAXED, __HIP_MEMORY_SCOPE_AGENT);
                int f3 = __hip_atomic_load(fl + 3, __ATOMIC_RELAXED, __HIP_MEMORY_SCOPE_AGENT);
                if ((f0 & f1 & f2 & f3) != 0) break;
                __builtin_amdgcn_s_sleep(2);
            }
            __threadfence();  // acquire: invalidate L1/L2 before reading h
            hsrc = h_buf + (size_t)(t - 1) * (32 * 256);
        }
        // stage h(t-1): iter i = env, lane handles quad l (coalesced 1 KB)
        for (int i = 0; i < 32; ++i) {
            float4 v = *(const float4*)(hsrc + i * 256 + l * 4);
            *(float4*)&hlds[i * 260 + l * 4] = v;
        }
        // single wave: lgkmcnt ordering suffices, no barrier needed
        int row = t * 32 + e;
        float m = 1.0f - (float)done[row];
        float4 a0 = {0.f, 0.f, 0.f, 0.f}, a1 = {0.f, 0.f, 0.f, 0.f};
        const float* hp = &hlds[e * 260];
#pragma unroll 8
        for (int k = 0; k < 256; k += 4) {
            float4 hk = *(const float4*)(hp + k);
            float4 w0 = *(const float4*)&wlds[g0][k];
            float4 w1 = *(const float4*)&wlds[g1][k];
            a0.x += hk.x * w0.x; a0.y += hk.y * w0.y;
            a0.z += hk.z * w0.z; a0.w += hk.w * w0.w;
            a1.x += hk.x * w1.x; a1.y += hk.y * w1.y;
            a1.z += hk.z * w1.z; a1.w += hk.w * w1.w;
        }
        float s0 = (a0.x + a0.y) + (a0.z + a0.w);
        float s1 = (a1.x + a1.y) + (a1.z + a1.w);
        float p0 = gi[(size_t)row * 1024 + g0 * 256 + u] + m * s0;
        float p1 = gi[(size_t)row * 1024 + g1 * 256 + u] + m * s1;
        float pf = __shfl(p0, e + 32, 64);  // f-gate pre-act from upper half
        float po = __shfl(p1, e + 32, 64);  // o-gate pre-act from upper half
        if (half == 0) {
            float gi_ = 1.0f / (1.0f + __expf(-p0));
            float gg  = tanhf(p1);
            float gf  = 1.0f / (1.0f + __expf(-pf));
            float go  = 1.0f / (1.0f + __expf(-po));
            c = gf * (c * m) + gi_ * gg;
            float hn = go * tanhf(c);
            h_buf[(size_t)t * (32 * 256) + e * 256 + u] = hn;
            out[(size_t)row * 256 + u] = hn;
        }
        __threadfence();  // release: drain h stores, write back L2
        if (l == 0) {
            __hip_atomic_store(&flags[t * 256 + u], 1, __ATOMIC_RELEASE,
                               __HIP_MEMORY_SCOPE_AGENT);
        }
    }
}

// ---------------------------------------------------------------------------
extern "C" void kernel_launch(void* const* d_in, const int* in_sizes, int n_in,
                              void* d_out, int out_size, void* d_ws, size_t ws_size,
                              hipStream_t stream) {
    const float* x    = (const float*)d_in[0];
    const int*   done = (const int*)d_in[1];
    const float* w1   = (const float*)d_in[2];
    const float* b1   = (const float*)d_in[3];
    const float* w2   = (const float*)d_in[4];
    const float* b2   = (const float*)d_in[5];
    const float* w3   = (const float*)d_in[6];
    const float* b3   = (const float*)d_in[7];
    const float* fcw  = (const float*)d_in[8];
    const float* fcb  = (const float*)d_in[9];
    const float* wih  = (const float*)d_in[10];
    const float* whh  = (const float*)d_in[11];
    const float* bih  = (const float*)d_in[12];
    const float* bhh  = (const float*)d_in[13];
    const float* h0   = (const float*)d_in[14];
    const float* c0   = (const float*)d_in[15];
    float* out = (float*)d_out;
    float* ws = (float*)d_ws;

    // workspace layout (floats). z1 region is reused by z3/feats/gi/h_buf/flags
    // (z1 dead after conv2; lstm scratch only live after gemms).
    float* z1    = ws + 0;          // 14,745,600
    float* z2    = ws + 14745600;   //  4,718,592 (ends 19,464,192)
    float* z3    = ws + 0;          //  2,097,152
    float* feats = ws + 2097152;    //  1,048,576
    float* gi    = ws + 3145728;    //  2,097,152 (ends 5,242,880)
    float* h_buf = ws + 5242880;    //    524,288 (ends 5,767,168)
    int*   flags = (int*)(ws + 5767168);  // 16,384 ints (ends 5,783,552)
    float* w2t   = ws + 19464192;   //     32,768
    float* w3t   = ws + 19496960;   //     36,864 (ends 19,533,824 = 78.1 MB)

    transpose_kernel<<<(64 * 512 + 255) / 256, 256, 0, stream>>>(w2, w2t, 64, 512);
    transpose_kernel<<<(64 * 576 + 255) / 256, 256, 0, stream>>>(w3, w3t, 64, 576);

    conv1_kernel<<<NIMG, 1024, 0, stream>>>(x, w1, b1, z1);
    conv2_kernel<<<NIMG / 2, 256, 0, stream>>>(z1, w2t, b2, z2);
    conv3_kernel<<<NIMG / 4, 256, 0, stream>>>(z2, w3t, b3, z3);

    gemm_bt<<<dim3(512 / 64, NIMG / 64), 256, 0, stream>>>(z3, fcw, fcb, nullptr, feats,
                                                           NIMG, 512, 1024, 1);
    gemm_bt<<<dim3(1024 / 64, NIMG / 64), 256, 0, stream>>>(feats, wih, bih, bhh, gi,
                                                            NIMG, 1024, 512, 0);

    hipMemsetAsync(flags, 0, 64 * 256 * sizeof(int), stream);
    lstm_kernel<<<256, 64, 0, stream>>>(gi, whh, done, h0, c0, h_buf, flags, out);
}

// Round 4
// 1194.950 us; speedup vs baseline: 1.7605x; 1.7605x over previous
//
#include <hip/hip_runtime.h>
#include <math.h>

// ---------------------------------------------------------------------------
// RecurrentNatureCNN: conv1(8x8,s4) -> conv2(4x4,s2) -> conv3(3x3,s1) -> FC
//                     -> LSTM(T=64,B=32,H=256)
// fp32. N = T*B = 2048 images.
// R3: LSTM back to 32 blocks x 1024 thr (no cross-block sync — R2's fence
//     pipeline cost 21.9 us/step). Weights pre-packed to w4[kq][j][4] so each
//     thread issues 64 coalesced dwordx4 loads/step instead of 256 scalar
//     dwords (R1's latency bound). conv2 768 thr, conv3 512 thr (occupancy).
// ---------------------------------------------------------------------------

#define NIMG 2048

// ---- generic small transpose: in (R,C) -> out (C,R) -----------------------
__global__ void transpose_kernel(const float* __restrict__ in, float* __restrict__ out,
                                 int R, int C) {
    int idx = blockIdx.x * 256 + threadIdx.x;
    if (idx < R * C) {
        int r = idx / C, c = idx - r * C;
        out[c * R + r] = in[idx];
    }
}

// ---- pack whh (1024,256) -> w4[kq][j][4], kq=k/4: thread j's quad kq is one
// float4 at ((kq*1024)+j)*4 — lane-coalesced dwordx4 in the LSTM inner loop.
__global__ void pack_whh_kernel(const float* __restrict__ whh, float* __restrict__ w4) {
    int idx = blockIdx.x * 256 + threadIdx.x;  // 0..65535 = kq*1024 + j
    int kq = idx >> 10, j = idx & 1023;
    float4 v = *(const float4*)(whh + (size_t)j * 256 + kq * 4);
    ((float4*)w4)[idx] = v;
}

// ---- conv1: x (n,4,64,64)/255 -> relu -> (n,32,15,15) ----------------------
// block = 1 image, 1024 threads (16 waves). wave w: oc-group g=w&3 (8 oc),
// position segment (w>>2)*64+lane. Image staged in LDS (64 KB -> 2 blocks/CU
// = 32 waves/CU).
__global__ __launch_bounds__(1024) void conv1_kernel(const float* __restrict__ x,
                                                     const float* __restrict__ w,
                                                     const float* __restrict__ b,
                                                     float* __restrict__ out) {
    __shared__ float xs[4 * 64 * 64];  // 65536 B
    int n = blockIdx.x;
    int tid = threadIdx.x;
    const float* xp = x + (size_t)n * 16384;
    const float inv = 1.0f / 255.0f;
    for (int i = tid * 4; i < 16384; i += 4096) {
        float4 v = *(const float4*)(xp + i);
        xs[i + 0] = v.x * inv;
        xs[i + 1] = v.y * inv;
        xs[i + 2] = v.z * inv;
        xs[i + 3] = v.w * inv;
    }
    __syncthreads();
    int lane = tid & 63, wave = tid >> 6;
    int gg = __builtin_amdgcn_readfirstlane(wave & 3);  // oc group, wave-uniform
    int pos = (wave >> 2) * 64 + lane;                  // 0..255
    if (pos < 225) {
        int oy = pos / 15, ox = pos - oy * 15;
        float acc[8];
        const float* bp = b + gg * 8;
#pragma unroll
        for (int u = 0; u < 8; ++u) acc[u] = bp[u];
        for (int ic = 0; ic < 4; ++ic) {
#pragma unroll
            for (int ky = 0; ky < 8; ++ky) {
                const float* xrow = &xs[(ic * 64 + oy * 4 + ky) * 64 + ox * 4];
                float xr[8];
                *(float4*)&xr[0] = *(const float4*)&xrow[0];
                *(float4*)&xr[4] = *(const float4*)&xrow[4];
                const float* wrow = w + (gg * 8) * 256 + ic * 64 + ky * 8;
#pragma unroll
                for (int u = 0; u < 8; ++u) {
                    const float* wr = wrow + u * 256;
#pragma unroll
                    for (int kx = 0; kx < 8; ++kx) acc[u] += xr[kx] * wr[kx];
                }
            }
        }
        float* op = out + (size_t)n * 7200 + (gg * 8) * 225 + pos;
#pragma unroll
        for (int u = 0; u < 8; ++u) op[u * 225] = fmaxf(acc[u], 0.0f);
    }
}

// ---- conv2: z1 (n,32,15,15) -> relu -> (n,64,6,6) --------------------------
// block = 2 images, 768 threads (12 waves). wave = (img, oy): one output row
// per wave, lane = out-channel. LDS rows padded to 16.
__global__ __launch_bounds__(768) void conv2_kernel(const float* __restrict__ x,
                                                    const float* __restrict__ wt,
                                                    const float* __restrict__ bias,
                                                    float* __restrict__ out) {
    __shared__ float xs[2][32 * 15 * 16];  // 61440 B
    int tid = threadIdx.x;
    int n0 = blockIdx.x * 2;
    for (int img = 0; img < 2; ++img) {
        const float* src = x + (size_t)(n0 + img) * 7200;
        for (int s = tid; s < 7200; s += 768) {
            int ic = s / 225;
            int rem = s - ic * 225;
            int r = rem / 15;
            int c = rem - r * 15;
            xs[img][(ic * 15 + r) * 16 + c] = src[s];
        }
    }
    __syncthreads();
    int lane = tid & 63, wave = tid >> 6;  // wave 0..11
    int img = wave / 6;
    int oy = wave - img * 6;
    int n = n0 + img;
    float bv = bias[lane];
    float* op = out + (size_t)n * 2304 + lane * 36;
    float acc[6];
#pragma unroll
    for (int u = 0; u < 6; ++u) acc[u] = bv;
    for (int ic = 0; ic < 32; ++ic) {
#pragma unroll
        for (int ky = 0; ky < 4; ++ky) {
            const float* xrow = &xs[img][(ic * 15 + oy * 2 + ky) * 16];
            float xr[16];
            *(float4*)&xr[0]  = *(const float4*)&xrow[0];
            *(float4*)&xr[4]  = *(const float4*)&xrow[4];
            *(float4*)&xr[8]  = *(const float4*)&xrow[8];
            *(float4*)&xr[12] = *(const float4*)&xrow[12];
            const float* wp = wt + ((ic * 4 + ky) * 4) * 64 + lane;
#pragma unroll
            for (int kx = 0; kx < 4; ++kx) {
                float wv = wp[kx * 64];
#pragma unroll
                for (int u = 0; u < 6; ++u) acc[u] += xr[u * 2 + kx] * wv;
            }
        }
    }
#pragma unroll
    for (int u = 0; u < 6; ++u) op[oy * 6 + u] = fmaxf(acc[u], 0.0f);
}

// ---- conv3: z2 (n,64,6,6) -> relu -> (n,64,4,4) ----------------------------
// block = 4 images, 512 threads (8 waves). wave = (img, oy-half): 2 output
// rows per wave, lane = out-channel. LDS rows padded to 8.
__global__ __launch_bounds__(512) void conv3_kernel(const float* __restrict__ x,
                                                    const float* __restrict__ wt,
                                                    const float* __restrict__ bias,
                                                    float* __restrict__ out) {
    __shared__ float xs[4][64 * 6 * 8];  // 49152 B
    int tid = threadIdx.x;
    int n0 = blockIdx.x * 4;
    for (int img = 0; img < 4; ++img) {
        const float* src = x + (size_t)(n0 + img) * 2304;
        for (int s = tid; s < 2304; s += 512) {
            int ic = s / 36;
            int rem = s - ic * 36;
            int r = rem / 6;
            int c = rem - r * 6;
            xs[img][(ic * 6 + r) * 8 + c] = src[s];
        }
    }
    __syncthreads();
    int lane = tid & 63, wave = tid >> 6;  // 0..7
    int img = wave >> 1;
    int half = wave & 1;
    int n = n0 + img;
    float bv = bias[lane];
    float* op = out + (size_t)n * 1024 + lane * 16;
    for (int q = 0; q < 2; ++q) {
        int oy = half * 2 + q;
        float acc[4];
#pragma unroll
        for (int u = 0; u < 4; ++u) acc[u] = bv;
        for (int ic = 0; ic < 64; ++ic) {
#pragma unroll
            for (int ky = 0; ky < 3; ++ky) {
                const float* xrow = &xs[img][(ic * 6 + oy + ky) * 8];
                float xr[8];
                *(float4*)&xr[0] = *(const float4*)&xrow[0];
                *(float4*)&xr[4] = *(const float4*)&xrow[4];
                const float* wp = wt + ((ic * 3 + ky) * 3) * 64 + lane;
#pragma unroll
                for (int kx = 0; kx < 3; ++kx) {
                    float wv = wp[kx * 64];
#pragma unroll
                    for (int u = 0; u < 4; ++u) acc[u] += xr[u + kx] * wv;
                }
            }
        }
#pragma unroll
        for (int u = 0; u < 4; ++u) op[oy * 4 + u] = fmaxf(acc[u], 0.0f);
    }
}

// ---- GEMM: C(M,N) = [relu]( A(M,K) @ B(N,K)^T + bias [+ bias2] ) -----------
__global__ __launch_bounds__(256) void gemm_bt(const float* __restrict__ A,
                                               const float* __restrict__ B,
                                               const float* __restrict__ bias,
                                               const float* __restrict__ bias2,
                                               float* __restrict__ C,
                                               int M, int N, int K, int relu) {
    __shared__ float As[16][68];
    __shared__ float Bs[16][68];
    int tid = threadIdx.x;
    int m0 = blockIdx.y * 64, n0 = blockIdx.x * 64;
    int tx = tid & 15, ty = tid >> 4;
    int lr = tid >> 2;
    int lk = (tid & 3) * 4;
    const float* Ap = A + (size_t)(m0 + lr) * K + lk;
    const float* Bp = B + (size_t)(n0 + lr) * K + lk;
    float acc[4][4];
#pragma unroll
    for (int i = 0; i < 4; ++i)
#pragma unroll
        for (int j = 0; j < 4; ++j) acc[i][j] = 0.0f;

    for (int k0 = 0; k0 < K; k0 += 16) {
        float4 av = *(const float4*)(Ap + k0);
        float4 bv = *(const float4*)(Bp + k0);
        __syncthreads();
        As[lk + 0][lr] = av.x;
        As[lk + 1][lr] = av.y;
        As[lk + 2][lr] = av.z;
        As[lk + 3][lr] = av.w;
        Bs[lk + 0][lr] = bv.x;
        Bs[lk + 1][lr] = bv.y;
        Bs[lk + 2][lr] = bv.z;
        Bs[lk + 3][lr] = bv.w;
        __syncthreads();
#pragma unroll
        for (int kk = 0; kk < 16; ++kk) {
            float a[4], b[4];
            *(float4*)a = *(const float4*)&As[kk][ty * 4];
            *(float4*)b = *(const float4*)&Bs[kk][tx * 4];
#pragma unroll
            for (int i = 0; i < 4; ++i)
#pragma unroll
                for (int j = 0; j < 4; ++j) acc[i][j] += a[i] * b[j];
        }
    }
    float bb[4];
#pragma unroll
    for (int j = 0; j < 4; ++j) {
        float v = bias[n0 + tx * 4 + j];
        if (bias2) v += bias2[n0 + tx * 4 + j];
        bb[j] = v;
    }
#pragma unroll
    for (int i = 0; i < 4; ++i) {
        float4 o;
        o.x = acc[i][0] + bb[0];
        o.y = acc[i][1] + bb[1];
        o.z = acc[i][2] + bb[2];
        o.w = acc[i][3] + bb[3];
        if (relu) {
            o.x = fmaxf(o.x, 0.0f);
            o.y = fmaxf(o.y, 0.0f);
            o.z = fmaxf(o.z, 0.0f);
            o.w = fmaxf(o.w, 0.0f);
        }
        *(float4*)&C[(size_t)(m0 + ty * 4 + i) * N + n0 + tx * 4] = o;
    }
}

// ---- LSTM: 32 blocks (one per env), 1024 threads ---------------------------
// gi (2048,1024) = feats@w_ih^T + b_ih + b_hh (precomputed). w4 = packed whh:
// thread j's K-quad kq is the float4 at (kq*1024 + j) -> coalesced dwordx4,
// 64 per thread per step (vs 256 scalar dwords in R1). h quads broadcast from
// LDS (same-address across the wave = free). Mask via (h*m)@W = m*(h@W).
__global__ __launch_bounds__(1024) void lstm_kernel(const float* __restrict__ gi,
                                                    const float* __restrict__ w4,
                                                    const int* __restrict__ done,
                                                    const float* __restrict__ h0,
                                                    const float* __restrict__ c0,
                                                    float* __restrict__ out) {
    __shared__ float h[256];
    __shared__ float gates[1024];
    int b = blockIdx.x, tid = threadIdx.x;
    float c = 0.0f;
    if (tid < 256) {
        c = c0[b * 256 + tid];
        h[tid] = h0[b * 256 + tid];
    }
    __syncthreads();
    const float4* wq = (const float4*)w4 + tid;  // + kq*1024
    for (int t = 0; t < 64; ++t) {
        int row = t * 32 + b;
        float m = 1.0f - (float)done[row];
        float gv = gi[(size_t)row * 1024 + tid];
        float4 a = {0.f, 0.f, 0.f, 0.f};
#pragma unroll 8
        for (int kq = 0; kq < 64; ++kq) {
            float4 hk = *(const float4*)&h[kq * 4];
            float4 w = wq[(size_t)kq * 1024];
            a.x += hk.x * w.x;
            a.y += hk.y * w.y;
            a.z += hk.z * w.z;
            a.w += hk.w * w.w;
        }
        float s = (a.x + a.y) + (a.z + a.w);
        gates[tid] = gv + m * s;
        __syncthreads();
        if (tid < 256) {
            float g_i = gates[tid];
            float g_f = gates[256 + tid];
            float g_g = gates[512 + tid];
            float g_o = gates[768 + tid];
            float si = 1.0f / (1.0f + __expf(-g_i));
            float sf = 1.0f / (1.0f + __expf(-g_f));
            float so = 1.0f / (1.0f + __expf(-g_o));
            float tg = tanhf(g_g);
            c = sf * (c * m) + si * tg;
            float hn = so * tanhf(c);
            h[tid] = hn;
            out[(size_t)row * 256 + tid] = hn;
        }
        __syncthreads();
    }
}

// ---------------------------------------------------------------------------
extern "C" void kernel_launch(void* const* d_in, const int* in_sizes, int n_in,
                              void* d_out, int out_size, void* d_ws, size_t ws_size,
                              hipStream_t stream) {
    const float* x    = (const float*)d_in[0];
    const int*   done = (const int*)d_in[1];
    const float* w1   = (const float*)d_in[2];
    const float* b1   = (const float*)d_in[3];
    const float* w2   = (const float*)d_in[4];
    const float* b2   = (const float*)d_in[5];
    const float* w3   = (const float*)d_in[6];
    const float* b3   = (const float*)d_in[7];
    const float* fcw  = (const float*)d_in[8];
    const float* fcb  = (const float*)d_in[9];
    const float* wih  = (const float*)d_in[10];
    const float* whh  = (const float*)d_in[11];
    const float* bih  = (const float*)d_in[12];
    const float* bhh  = (const float*)d_in[13];
    const float* h0   = (const float*)d_in[14];
    const float* c0   = (const float*)d_in[15];
    float* out = (float*)d_out;
    float* ws = (float*)d_ws;

    // workspace layout (floats). z3/feats/gi reuse z1's region (z1 dead then).
    float* z1    = ws + 0;          // 14,745,600
    float* z2    = ws + 14745600;   //  4,718,592 (ends 19,464,192)
    float* z3    = ws + 0;          //  2,097,152
    float* feats = ws + 2097152;    //  1,048,576
    float* gi    = ws + 3145728;    //  2,097,152 (ends 5,242,880)
    float* w2t   = ws + 19464192;   //     32,768
    float* w3t   = ws + 19496960;   //     36,864
    float* w4    = ws + 19533824;   //    262,144 (ends 19,795,968 -> 79.2 MB)

    transpose_kernel<<<(64 * 512 + 255) / 256, 256, 0, stream>>>(w2, w2t, 64, 512);
    transpose_kernel<<<(64 * 576 + 255) / 256, 256, 0, stream>>>(w3, w3t, 64, 576);
    pack_whh_kernel<<<256, 256, 0, stream>>>(whh, w4);

    conv1_kernel<<<NIMG, 1024, 0, stream>>>(x, w1, b1, z1);
    conv2_kernel<<<NIMG / 2, 768, 0, stream>>>(z1, w2t, b2, z2);
    conv3_kernel<<<NIMG / 4, 512, 0, stream>>>(z2, w3t, b3, z3);

    gemm_bt<<<dim3(512 / 64, NIMG / 64), 256, 0, stream>>>(z3, fcw, fcb, nullptr, feats,
                                                           NIMG, 512, 1024, 1);
    gemm_bt<<<dim3(1024 / 64, NIMG / 64), 256, 0, stream>>>(feats, wih, bih, bhh, gi,
                                                            NIMG, 1024, 512, 0);

    lstm_kernel<<<32, 1024, 0, stream>>>(gi, w4, done, h0, c0, out);
}